// Round 6
// baseline (107.363 us; speedup 1.0000x reference)
//
#include <hip/hip_runtime.h>
#include <cstdint>
#include <cstddef>

// VanillaRNN: B=4096, T=512, H=128, C=10
// Round 6: INSTRUMENTED round. Kernel launched 3x back-to-back (idempotent:
// reads d_in only, writes d_out deterministically) so dur_us solves for the
// kernel's own time: dur = floor(~53) + k_cold + 2*k_warm + gaps. Round-2
// arithmetic says floor = 52.7 (303.8 - 251.1 measured); kernel-time model
// (~8-10us) vs floor-arithmetic (~27us) contradict - this measures which.
// Micro-opts vs r5 (both safe):
//  - B-fragment ds_reads hoisted above the flag-gated branch; flag ds_read
//    issued first => compiler gates the branch on lgkmcnt(8), B-read latency
//    overlaps the flag wait (~-120 cyc/heavy step).
//  - correction accumulator split a1 -> a1a + a1b: two independent 4-MFMA
//    dependency chains instead of one 8-chain (~-80 cyc/step). Changes
//    correction-term rounding ~1e-6 abs - no flip risk (flip window needs
//    ~2e-2 per round 1).
// Skip validity (unchanged from r4/r5): stable (h==h_prev, all |pre|>10 =>
// h=+-1 exact, accWh current) => step t identity iff |x_t[b]| < X_b,
// X_b = min_i (c_i h_i - 10.5)/|Whx_i| ~ 43 sigma => ~zero violations.

#define TLEN 512
#define HDIM 128
#define NCLS 10
#define HS   136                   // h column stride in f16 (272 B, 16B-aligned)
#define LIMBSTRIDE (16 * HS)
#define PARSTRIDE  (2 * LIMBSTRIDE)
#define XSF  516                   // x stage row stride in floats (2-way banks)

typedef _Float16 f16x8 __attribute__((ext_vector_type(8)));
typedef float    f32x4 __attribute__((ext_vector_type(4)));

union PK4 { _Float16 h[4]; uint2 u; };

__device__ __forceinline__ float tanh_fast(float x) {
    // tanh(x) = 1 - 2/(e^{2x}+1); exact +-1.0f for |x|>10 after fp32 rounding
    float e = __expf(2.0f * x);
    return 1.0f - 2.0f * __builtin_amdgcn_rcpf(e + 1.0f);
}

__global__ __launch_bounds__(256, 1) void rnn_kernel(
    const float* __restrict__ x,    // [B,T]
    const float* __restrict__ Whx,  // [H]
    const float* __restrict__ Whh,  // [H,H]
    const float* __restrict__ Wph,  // [C,H]
    const float* __restrict__ bh,   // [H]
    const float* __restrict__ bp,   // [C]
    float* __restrict__ out)        // [B,C]
{
    __shared__ _Float16 hbuf[2 * PARSTRIDE];   // [parity][limb][col][k]
    __shared__ float    xs[16 * XSF];          // [col][t]
    __shared__ unsigned flagw[2];              // byte w: bit0 changed, bit1 sat
    __shared__ unsigned Xs[16];
    __shared__ unsigned vmask[16] __attribute__((aligned(16)));

    const int tid  = threadIdx.x;
    const int w    = tid >> 6;     // wave 0..3: rows [32w, 32w+32)
    const int lane = tid & 63;
    const int n    = lane & 15;    // MFMA col (batch)
    const int q    = lane >> 4;    // quad
    const int blk  = blockIdx.x;

    // ---- x prefetch into registers, then stage to LDS ----
    const int xrow = tid >> 4, xsl = tid & 15;
    {
        const float* xp = &x[(size_t)(blk * 16 + xrow) * TLEN];
        f32x4 xr0[8];
        #pragma unroll
        for (int j = 0; j < 8; ++j)
            xr0[j] = *(const f32x4*)&xp[64 * j + 4 * xsl];
        #pragma unroll
        for (int j = 0; j < 8; ++j)
            *(f32x4*)&xs[xrow * XSF + 64 * j + 4 * xsl] = xr0[j];
    }

    // ---- W_hh fragments, two f16 limbs: A[m=lane&15][k=8q+j] per 32-k chunk ----
    f16x8 w1[2][4], w2[2][4];
    #pragma unroll
    for (int u = 0; u < 2; ++u) {
        #pragma unroll
        for (int kc = 0; kc < 4; ++kc) {
            const int row = 32 * w + 16 * u + n;
            const float* wp = &Whh[row * HDIM + 32 * kc + 8 * q];
            #pragma unroll
            for (int j = 0; j < 8; ++j) {
                const float v = wp[j];
                const _Float16 a = (_Float16)v;
                w1[u][kc][j] = a;
                w2[u][kc][j] = (_Float16)((v - (float)a) * 2048.0f);
            }
        }
    }
    // per-lane row constants: acc element (u,r) -> row 32w + 16u + 4q + r
    float wx[8], bb[8];
    #pragma unroll
    for (int u = 0; u < 2; ++u)
        #pragma unroll
        for (int r = 0; r < 4; ++r) {
            const int row = 32 * w + 16 * u + 4 * q + r;
            wx[4 * u + r] = Whx[row];
            bb[4 * u + r] = bh[row];
        }

    for (int i = tid; i < 2 * PARSTRIDE; i += 256) hbuf[i] = (_Float16)0.0f;
    if (tid == 0) { flagw[0] = 0x01010101u; flagw[1] = 0u; }
    __syncthreads();

    float accWh[8], h_prev[8], hv[8];
    #pragma unroll
    for (int i = 0; i < 8; ++i) { accWh[i] = 0.0f; h_prev[i] = 0.0f; }
    int p = 0;                     // parity of hbuf holding current h
    int sp = 0;                    // flag-word parity (per executed step)
    bool maskvalid = false;
    unsigned vm[16];

    auto writeLimbs = [&](int par) {
        #pragma unroll
        for (int u = 0; u < 2; ++u) {
            PK4 p1, p2;
            #pragma unroll
            for (int r = 0; r < 4; ++r) {
                const float v = hv[4 * u + r];
                const _Float16 hh = (_Float16)v;
                p1.h[r] = hh;
                p2.h[r] = (_Float16)((v - (float)hh) * 2048.0f);
            }
            const int kb = 32 * w + 16 * u + 4 * q;
            *(uint2*)&hbuf[par * PARSTRIDE +              n * HS + kb] = p1.u;
            *(uint2*)&hbuf[par * PARSTRIDE + LIMBSTRIDE + n * HS + kb] = p2.u;
        }
    };

    int t = 0;
    while (t < TLEN) {
        const unsigned fw = flagw[sp];                 // issued first -> gate on lgkmcnt(8)
        // unconditional B-fragment prefetch from hbuf[p] (always current h);
        // latency overlaps the flag wait instead of serializing after it
        const _Float16* hb = &hbuf[p * PARSTRIDE];
        f16x8 b1[4], b2[4];
        #pragma unroll
        for (int kc = 0; kc < 4; ++kc) {
            b1[kc] = *(const f16x8*)&hb[             n * HS + 32 * kc + 8 * q];
            b2[kc] = *(const f16x8*)&hb[LIMBSTRIDE + n * HS + 32 * kc + 8 * q];
        }

        const bool heavy  = (fw & 0x01010101u) != 0u;  // someone's h changed
        const bool allsat = (fw & 0x02020202u) == 0x02020202u;
        if (heavy) maskvalid = false;                  // block-uniform
        bool do_heavy = heavy;

        if (!heavy && allsat) {
            // ---- stable: h frozen at exact +-1, accWh current ----
            if (!maskvalid) {
                if (tid < 16) { Xs[tid] = 0x7f800000u; vmask[tid] = 0u; }
                float m8 = 3.0e38f;
                #pragma unroll
                for (int i = 0; i < 8; ++i) {
                    const float c  = accWh[i] + bb[i];
                    const float mi = (c * h_prev[i] - 10.5f) / fmaxf(fabsf(wx[i]), 1e-30f);
                    m8 = fminf(m8, mi);
                }
                m8 = fmaxf(m8, 0.0f);                  // nonneg: uint order ok
                __syncthreads();
                atomicMin(&Xs[n], __float_as_uint(m8));
                __syncthreads();
                const float Xc = __uint_as_float(Xs[xrow]);
                const float* xrp = &xs[xrow * XSF];
                #pragma unroll
                for (int j = 0; j < 8; ++j) {
                    unsigned nib = 0u;
                    #pragma unroll
                    for (int m = 0; m < 4; ++m)
                        if (fabsf(xrp[64 * j + 4 * xsl + m]) >= Xc) nib |= (1u << m);
                    if (nib) atomicOr(&vmask[2 * j + (xsl >> 3)], nib << (4 * (xsl & 7)));
                }
                __syncthreads();
                #pragma unroll
                for (int k = 0; k < 4; ++k) {
                    const uint4 v4 = *(const uint4*)&vmask[4 * k];
                    vm[4 * k] = v4.x; vm[4 * k + 1] = v4.y;
                    vm[4 * k + 2] = v4.z; vm[4 * k + 3] = v4.w;
                }
                maskvalid = true;
            }
            // next violation >= t (register ffs; block-uniform)
            int nt = TLEN;
            #pragma unroll
            for (int wd = 15; wd >= 0; --wd) {
                const int base = 32 * wd;
                unsigned mm = vm[wd];
                mm = (base + 31 < t) ? 0u
                   : ((base < t) ? (mm & ~((1u << (t - base)) - 1u)) : mm);
                if (mm) nt = base + __ffs(mm) - 1;
            }
            if (nt >= TLEN) break;        // identity to the end
            t = nt;                       // steps [t, nt) are identity
            do_heavy = false;             // accWh current; light step at nt
        }

        // ---- execute one step at time t ----
        const float xt = xs[n * XSF + t];

        if (do_heavy) {
            #pragma unroll
            for (int u = 0; u < 2; ++u) {
                f32x4 a0  = {0.0f, 0.0f, 0.0f, 0.0f};
                f32x4 a1a = {0.0f, 0.0f, 0.0f, 0.0f};
                f32x4 a1b = {0.0f, 0.0f, 0.0f, 0.0f};
                #pragma unroll
                for (int kc = 0; kc < 4; ++kc) {
                    a0  = __builtin_amdgcn_mfma_f32_16x16x32_f16(w1[u][kc], b1[kc], a0,  0, 0, 0);
                    a1a = __builtin_amdgcn_mfma_f32_16x16x32_f16(w1[u][kc], b2[kc], a1a, 0, 0, 0);
                    a1b = __builtin_amdgcn_mfma_f32_16x16x32_f16(w2[u][kc], b1[kc], a1b, 0, 0, 0);
                }
                #pragma unroll
                for (int r = 0; r < 4; ++r)
                    accWh[4 * u + r] = fmaf(a1a[r] + a1b[r], 0x1p-11f, a0[r]);
            }
        }

        float pre[8];
        #pragma unroll
        for (int i = 0; i < 8; ++i)
            pre[i] = accWh[i] + fmaf(wx[i], xt, bb[i]);

        bool sat = true;
        #pragma unroll
        for (int i = 0; i < 8; ++i) sat = sat && (fabsf(pre[i]) > 10.0f);
        const bool wave_sat = (__ballot(sat) == ~0ull);
        if (wave_sat) {
            #pragma unroll
            for (int i = 0; i < 8; ++i) hv[i] = copysignf(1.0f, pre[i]);
        } else {
            #pragma unroll
            for (int i = 0; i < 8; ++i) hv[i] = tanh_fast(pre[i]);
        }

        bool eq = true;
        #pragma unroll
        for (int i = 0; i < 8; ++i) eq = eq && (hv[i] == h_prev[i]);
        const bool wave_changed = (__ballot(eq) != ~0ull);
        #pragma unroll
        for (int i = 0; i < 8; ++i) h_prev[i] = hv[i];

        if (do_heavy) {
            writeLimbs(p ^ 1);
            p ^= 1;
        } else if (wave_changed) {
            writeLimbs(0);                 // keep both parities current
            writeLimbs(1);
        }
        if (lane == 0)
            ((unsigned char*)&flagw[sp ^ 1])[w] =
                (unsigned char)((wave_changed ? 1u : 0u) | (wave_sat ? 2u : 0u));
        __syncthreads();
        sp ^= 1;
        ++t;
    }

    // ---- projection: out[b][co] = sum_i Wph[co][i]*h_T[i][b] + bp[co] ----
    if (tid < 16 * NCLS) {
        const int c  = tid / NCLS;
        const int co = tid - c * NCLS;
        const _Float16* h1 = &hbuf[p * PARSTRIDE +              c * HS];
        const _Float16* h2 = &hbuf[p * PARSTRIDE + LIMBSTRIDE + c * HS];
        float s = bp[co];
        #pragma unroll 8
        for (int i = 0; i < HDIM; ++i)
            s = fmaf(Wph[co * HDIM + i],
                     (float)h1[i] + (float)h2[i] * (1.0f / 2048.0f), s);
        out[((size_t)blk * 16 + c) * NCLS + co] = s;
    }
}

extern "C" void kernel_launch(void* const* d_in, const int* in_sizes, int n_in,
                              void* d_out, int out_size, void* d_ws, size_t ws_size,
                              hipStream_t stream) {
    const float* x   = (const float*)d_in[0];  // [4096,512]
    const float* Whx = (const float*)d_in[1];  // [128,1]
    const float* Whh = (const float*)d_in[2];  // [128,128]
    const float* Wph = (const float*)d_in[3];  // [10,128]
    const float* bh  = (const float*)d_in[4];  // [128,1]
    const float* bp  = (const float*)d_in[5];  // [10,1]
    float* out = (float*)d_out;                // [4096,10]

    // 3x launch: idempotent (reads d_in only; d_out rewritten identically).
    // dur_us = floor + k_cold + 2*k_warm + gaps -> solves for kernel time.
    for (int rep = 0; rep < 3; ++rep)
        rnn_kernel<<<dim3(256), dim3(256), 0, stream>>>(x, Whx, Whh, Wph, bh, bp, out);
}

// Round 7
// 83.960 us; speedup vs baseline: 1.2787x; 1.2787x over previous
//
#include <hip/hip_runtime.h>
#include <cstdint>
#include <cstddef>

// VanillaRNN: B=4096, T=512, H=128, C=10
// Round 7: r6 structure, single main launch, PLUS a warm-up kernel.
// r6 instrumentation (3x launch): warm kernel ~11-13us, cold ~27.8us
// => ~14-16us cold-memory penalty. Theory: the 256MiB 0xAA ws-poison right
// before the kernel dirties all of L3/L2, evicting x; the main kernel's
// blocking x-prefetch + per-block Whh reads then miss everywhere and queue
// behind the 256MiB writeback drain - on the serial critical path.
// Fix: a TLP-rich, BW-bound warm-up kernel streams x/Whh/Wph/biases into
// L2/L3 first (absorbs the cold-queue cost in ~3us with no serial chain);
// the main kernel then runs L2/L3-warm. Deterministic d_ws writes defeat DCE.
// Main kernel numerics identical to r6 (passed, absmax 0.0).

#define TLEN 512
#define HDIM 128
#define NCLS 10
#define HS   136                   // h column stride in f16 (272 B, 16B-aligned)
#define LIMBSTRIDE (16 * HS)
#define PARSTRIDE  (2 * LIMBSTRIDE)
#define XSF  516                   // x stage row stride in floats (2-way banks)

typedef _Float16 f16x8 __attribute__((ext_vector_type(8)));
typedef float    f32x4 __attribute__((ext_vector_type(4)));

union PK4 { _Float16 h[4]; uint2 u; };

__device__ __forceinline__ float tanh_fast(float x) {
    // tanh(x) = 1 - 2/(e^{2x}+1); exact +-1.0f for |x|>10 after fp32 rounding
    float e = __expf(2.0f * x);
    return 1.0f - 2.0f * __builtin_amdgcn_rcpf(e + 1.0f);
}

// ---- warm-up: stream the main kernel's working set into L2/L3 ----
__global__ __launch_bounds__(256, 1) void warm_kernel(
    const float* __restrict__ x,
    const float* __restrict__ Whx,
    const float* __restrict__ Whh,
    const float* __restrict__ Wph,
    const float* __restrict__ bh,
    const float* __restrict__ bp,
    float* __restrict__ ws)
{
    const int tid = threadIdx.x, blk = blockIdx.x;
    float s = 0.0f;
    // this block's x slice (same blockIdx->XCD mapping as the main kernel)
    const f32x4* xp = (const f32x4*)&x[(size_t)blk * 16 * TLEN];
    #pragma unroll 4
    for (int i = tid; i < 16 * TLEN / 4; i += 256) {
        const f32x4 v = xp[i]; s += v.x + v.y + v.z + v.w;
    }
    const f32x4* wp = (const f32x4*)Whh;
    #pragma unroll 4
    for (int i = tid; i < HDIM * HDIM / 4; i += 256) {
        const f32x4 v = wp[i]; s += v.x + v.y + v.z + v.w;
    }
    const f32x4* pp = (const f32x4*)Wph;
    for (int i = tid; i < NCLS * HDIM / 4; i += 256) {
        const f32x4 v = pp[i]; s += v.x + v.y + v.z + v.w;
    }
    if (tid < HDIM) s += Whx[tid] + bh[tid];
    if (tid < NCLS) s += bp[tid];
    ws[(size_t)blk * 256 + tid] = s;   // deterministic; defeats DCE
}

__global__ __launch_bounds__(256, 1) void rnn_kernel(
    const float* __restrict__ x,    // [B,T]
    const float* __restrict__ Whx,  // [H]
    const float* __restrict__ Whh,  // [H,H]
    const float* __restrict__ Wph,  // [C,H]
    const float* __restrict__ bh,   // [H]
    const float* __restrict__ bp,   // [C]
    float* __restrict__ out)        // [B,C]
{
    __shared__ _Float16 hbuf[2 * PARSTRIDE];   // [parity][limb][col][k]
    __shared__ float    xs[16 * XSF];          // [col][t]
    __shared__ unsigned flagw[2];              // byte w: bit0 changed, bit1 sat
    __shared__ unsigned Xs[16];
    __shared__ unsigned vmask[16] __attribute__((aligned(16)));

    const int tid  = threadIdx.x;
    const int w    = tid >> 6;     // wave 0..3: rows [32w, 32w+32)
    const int lane = tid & 63;
    const int n    = lane & 15;    // MFMA col (batch)
    const int q    = lane >> 4;    // quad
    const int blk  = blockIdx.x;

    // ---- x prefetch into registers, then stage to LDS ----
    const int xrow = tid >> 4, xsl = tid & 15;
    {
        const float* xp = &x[(size_t)(blk * 16 + xrow) * TLEN];
        f32x4 xr0[8];
        #pragma unroll
        for (int j = 0; j < 8; ++j)
            xr0[j] = *(const f32x4*)&xp[64 * j + 4 * xsl];
        #pragma unroll
        for (int j = 0; j < 8; ++j)
            *(f32x4*)&xs[xrow * XSF + 64 * j + 4 * xsl] = xr0[j];
    }

    // ---- W_hh fragments, two f16 limbs: A[m=lane&15][k=8q+j] per 32-k chunk ----
    f16x8 w1[2][4], w2[2][4];
    #pragma unroll
    for (int u = 0; u < 2; ++u) {
        #pragma unroll
        for (int kc = 0; kc < 4; ++kc) {
            const int row = 32 * w + 16 * u + n;
            const float* wp = &Whh[row * HDIM + 32 * kc + 8 * q];
            #pragma unroll
            for (int j = 0; j < 8; ++j) {
                const float v = wp[j];
                const _Float16 a = (_Float16)v;
                w1[u][kc][j] = a;
                w2[u][kc][j] = (_Float16)((v - (float)a) * 2048.0f);
            }
        }
    }
    // per-lane row constants: acc element (u,r) -> row 32w + 16u + 4q + r
    float wx[8], bb[8];
    #pragma unroll
    for (int u = 0; u < 2; ++u)
        #pragma unroll
        for (int r = 0; r < 4; ++r) {
            const int row = 32 * w + 16 * u + 4 * q + r;
            wx[4 * u + r] = Whx[row];
            bb[4 * u + r] = bh[row];
        }

    for (int i = tid; i < 2 * PARSTRIDE; i += 256) hbuf[i] = (_Float16)0.0f;
    if (tid == 0) { flagw[0] = 0x01010101u; flagw[1] = 0u; }
    __syncthreads();

    float accWh[8], h_prev[8], hv[8];
    #pragma unroll
    for (int i = 0; i < 8; ++i) { accWh[i] = 0.0f; h_prev[i] = 0.0f; }
    int p = 0;                     // parity of hbuf holding current h
    int sp = 0;                    // flag-word parity (per executed step)
    bool maskvalid = false;
    unsigned vm[16];

    auto writeLimbs = [&](int par) {
        #pragma unroll
        for (int u = 0; u < 2; ++u) {
            PK4 p1, p2;
            #pragma unroll
            for (int r = 0; r < 4; ++r) {
                const float v = hv[4 * u + r];
                const _Float16 hh = (_Float16)v;
                p1.h[r] = hh;
                p2.h[r] = (_Float16)((v - (float)hh) * 2048.0f);
            }
            const int kb = 32 * w + 16 * u + 4 * q;
            *(uint2*)&hbuf[par * PARSTRIDE +              n * HS + kb] = p1.u;
            *(uint2*)&hbuf[par * PARSTRIDE + LIMBSTRIDE + n * HS + kb] = p2.u;
        }
    };

    int t = 0;
    while (t < TLEN) {
        const unsigned fw = flagw[sp];                 // issued first -> gate on lgkmcnt
        // unconditional B-fragment prefetch from hbuf[p] (always current h);
        // latency overlaps the flag wait instead of serializing after it
        const _Float16* hb = &hbuf[p * PARSTRIDE];
        f16x8 b1[4], b2[4];
        #pragma unroll
        for (int kc = 0; kc < 4; ++kc) {
            b1[kc] = *(const f16x8*)&hb[             n * HS + 32 * kc + 8 * q];
            b2[kc] = *(const f16x8*)&hb[LIMBSTRIDE + n * HS + 32 * kc + 8 * q];
        }

        const bool heavy  = (fw & 0x01010101u) != 0u;  // someone's h changed
        const bool allsat = (fw & 0x02020202u) == 0x02020202u;
        if (heavy) maskvalid = false;                  // block-uniform
        bool do_heavy = heavy;

        if (!heavy && allsat) {
            // ---- stable: h frozen at exact +-1, accWh current ----
            if (!maskvalid) {
                if (tid < 16) { Xs[tid] = 0x7f800000u; vmask[tid] = 0u; }
                float m8 = 3.0e38f;
                #pragma unroll
                for (int i = 0; i < 8; ++i) {
                    const float c  = accWh[i] + bb[i];
                    const float mi = (c * h_prev[i] - 10.5f) / fmaxf(fabsf(wx[i]), 1e-30f);
                    m8 = fminf(m8, mi);
                }
                m8 = fmaxf(m8, 0.0f);                  // nonneg: uint order ok
                __syncthreads();
                atomicMin(&Xs[n], __float_as_uint(m8));
                __syncthreads();
                const float Xc = __uint_as_float(Xs[xrow]);
                const float* xrp = &xs[xrow * XSF];
                #pragma unroll
                for (int j = 0; j < 8; ++j) {
                    unsigned nib = 0u;
                    #pragma unroll
                    for (int m = 0; m < 4; ++m)
                        if (fabsf(xrp[64 * j + 4 * xsl + m]) >= Xc) nib |= (1u << m);
                    if (nib) atomicOr(&vmask[2 * j + (xsl >> 3)], nib << (4 * (xsl & 7)));
                }
                __syncthreads();
                #pragma unroll
                for (int k = 0; k < 4; ++k) {
                    const uint4 v4 = *(const uint4*)&vmask[4 * k];
                    vm[4 * k] = v4.x; vm[4 * k + 1] = v4.y;
                    vm[4 * k + 2] = v4.z; vm[4 * k + 3] = v4.w;
                }
                maskvalid = true;
            }
            // next violation >= t (register ffs; block-uniform)
            int nt = TLEN;
            #pragma unroll
            for (int wd = 15; wd >= 0; --wd) {
                const int base = 32 * wd;
                unsigned mm = vm[wd];
                mm = (base + 31 < t) ? 0u
                   : ((base < t) ? (mm & ~((1u << (t - base)) - 1u)) : mm);
                if (mm) nt = base + __ffs(mm) - 1;
            }
            if (nt >= TLEN) break;        // identity to the end
            t = nt;                       // steps [t, nt) are identity
            do_heavy = false;             // accWh current; light step at nt
        }

        // ---- execute one step at time t ----
        const float xt = xs[n * XSF + t];

        if (do_heavy) {
            #pragma unroll
            for (int u = 0; u < 2; ++u) {
                f32x4 a0  = {0.0f, 0.0f, 0.0f, 0.0f};
                f32x4 a1a = {0.0f, 0.0f, 0.0f, 0.0f};
                f32x4 a1b = {0.0f, 0.0f, 0.0f, 0.0f};
                #pragma unroll
                for (int kc = 0; kc < 4; ++kc) {
                    a0  = __builtin_amdgcn_mfma_f32_16x16x32_f16(w1[u][kc], b1[kc], a0,  0, 0, 0);
                    a1a = __builtin_amdgcn_mfma_f32_16x16x32_f16(w1[u][kc], b2[kc], a1a, 0, 0, 0);
                    a1b = __builtin_amdgcn_mfma_f32_16x16x32_f16(w2[u][kc], b1[kc], a1b, 0, 0, 0);
                }
                #pragma unroll
                for (int r = 0; r < 4; ++r)
                    accWh[4 * u + r] = fmaf(a1a[r] + a1b[r], 0x1p-11f, a0[r]);
            }
        }

        float pre[8];
        #pragma unroll
        for (int i = 0; i < 8; ++i)
            pre[i] = accWh[i] + fmaf(wx[i], xt, bb[i]);

        bool sat = true;
        #pragma unroll
        for (int i = 0; i < 8; ++i) sat = sat && (fabsf(pre[i]) > 10.0f);
        const bool wave_sat = (__ballot(sat) == ~0ull);
        if (wave_sat) {
            #pragma unroll
            for (int i = 0; i < 8; ++i) hv[i] = copysignf(1.0f, pre[i]);
        } else {
            #pragma unroll
            for (int i = 0; i < 8; ++i) hv[i] = tanh_fast(pre[i]);
        }

        bool eq = true;
        #pragma unroll
        for (int i = 0; i < 8; ++i) eq = eq && (hv[i] == h_prev[i]);
        const bool wave_changed = (__ballot(eq) != ~0ull);
        #pragma unroll
        for (int i = 0; i < 8; ++i) h_prev[i] = hv[i];

        if (do_heavy) {
            writeLimbs(p ^ 1);
            p ^= 1;
        } else if (wave_changed) {
            writeLimbs(0);                 // keep both parities current
            writeLimbs(1);
        }
        if (lane == 0)
            ((unsigned char*)&flagw[sp ^ 1])[w] =
                (unsigned char)((wave_changed ? 1u : 0u) | (wave_sat ? 2u : 0u));
        __syncthreads();
        sp ^= 1;
        ++t;
    }

    // ---- projection: out[b][co] = sum_i Wph[co][i]*h_T[i][b] + bp[co] ----
    if (tid < 16 * NCLS) {
        const int c  = tid / NCLS;
        const int co = tid - c * NCLS;
        const _Float16* h1 = &hbuf[p * PARSTRIDE +              c * HS];
        const _Float16* h2 = &hbuf[p * PARSTRIDE + LIMBSTRIDE + c * HS];
        float s = bp[co];
        #pragma unroll 8
        for (int i = 0; i < HDIM; ++i)
            s = fmaf(Wph[co * HDIM + i],
                     (float)h1[i] + (float)h2[i] * (1.0f / 2048.0f), s);
        out[((size_t)blk * 16 + c) * NCLS + co] = s;
    }
}

extern "C" void kernel_launch(void* const* d_in, const int* in_sizes, int n_in,
                              void* d_out, int out_size, void* d_ws, size_t ws_size,
                              hipStream_t stream) {
    const float* x   = (const float*)d_in[0];  // [4096,512]
    const float* Whx = (const float*)d_in[1];  // [128,1]
    const float* Whh = (const float*)d_in[2];  // [128,128]
    const float* Wph = (const float*)d_in[3];  // [10,128]
    const float* bh  = (const float*)d_in[4];  // [128,1]
    const float* bp  = (const float*)d_in[5];  // [10,1]
    float* out = (float*)d_out;                // [4096,10]
    float* ws  = (float*)d_ws;                 // scratch (warm-up sums)

    warm_kernel<<<dim3(256), dim3(256), 0, stream>>>(x, Whx, Whh, Wph, bh, bp, ws);
    rnn_kernel <<<dim3(256), dim3(256), 0, stream>>>(x, Whx, Whh, Wph, bh, bp, out);
}

// Round 8
// 77.793 us; speedup vs baseline: 1.3801x; 1.0793x over previous
//
#include <hip/hip_runtime.h>
#include <cstdint>
#include <cstddef>

// VanillaRNN: B=4096, T=512, H=128, C=10
// Round 8: r6 algorithm (two-limb f16 MFMA transient + saturation lock +
// bitmask time-skip), single launch (r7's warm-up kernel REVERTED: it ran in
// ~2us with no cold penalty yet transferred no speedup -> the cold/warm delta
// is kernel-instance-bound (DVFS ramp + serial transient), not cache state).
// Serial-chain cuts vs r6 (executed-step numerics bit-identical):
//  - t=0 special-cased (h=0: no flags, no B-prefetch, no MFMA) and hbuf
//    zero-init dropped (parity 1 fully written at t=0; parity 0 first
//    written by the first heavy step before any read of it).
//  - W-limb conversion moved after step-0 (global W loads issued before the
//    first barrier; ~400cyc VALU conversion overlaps step-0's LDS drain).
//  - light-changed steps write ONE parity (p) - the only one ever read;
//    same-step prefetch reads of p are discarded (light), so benign race.
//  - projection epilogue vectorized (f16x8 LDS reads).
// Skip validity (unchanged): stable (h==h_prev, all |pre|>10 => h=+-1 exact,
// accWh current) => step t identity iff |x_t[b]| < X_b,
// X_b = min_i (c_i h_i - 10.5)/|Whx_i|; margin => ballot-all-sat path
// returns copysign == h_prev, bit-identical to executing.

#define TLEN 512
#define HDIM 128
#define NCLS 10
#define HS   136                   // h column stride in f16 (272 B, 16B-aligned)
#define LIMBSTRIDE (16 * HS)
#define PARSTRIDE  (2 * LIMBSTRIDE)
#define XSF  516                   // x stage row stride in floats (2-way banks)

typedef _Float16 f16x8 __attribute__((ext_vector_type(8)));
typedef float    f32x4 __attribute__((ext_vector_type(4)));

union PK4 { _Float16 h[4]; uint2 u; };

__device__ __forceinline__ float tanh_fast(float x) {
    // tanh(x) = 1 - 2/(e^{2x}+1); exact +-1.0f for |x|>10 after fp32 rounding
    float e = __expf(2.0f * x);
    return 1.0f - 2.0f * __builtin_amdgcn_rcpf(e + 1.0f);
}

__global__ __launch_bounds__(256, 1) void rnn_kernel(
    const float* __restrict__ x,    // [B,T]
    const float* __restrict__ Whx,  // [H]
    const float* __restrict__ Whh,  // [H,H]
    const float* __restrict__ Wph,  // [C,H]
    const float* __restrict__ bh,   // [H]
    const float* __restrict__ bp,   // [C]
    float* __restrict__ out)        // [B,C]
{
    __shared__ _Float16 hbuf[2 * PARSTRIDE];   // [parity][limb][col][k]; NO init
    __shared__ float    xs[16 * XSF];          // [col][t]
    __shared__ unsigned flagw[2];              // byte w: bit0 changed, bit1 sat
    __shared__ unsigned Xs[16];
    __shared__ unsigned vmask[16] __attribute__((aligned(16)));

    const int tid  = threadIdx.x;
    const int w    = tid >> 6;     // wave 0..3: rows [32w, 32w+32)
    const int lane = tid & 63;
    const int n    = lane & 15;    // MFMA col (batch)
    const int q    = lane >> 4;    // quad
    const int blk  = blockIdx.x;

    // ---- x load (coalesced float4) and stage to LDS ----
    const int xrow = tid >> 4, xsl = tid & 15;
    {
        const float* xp = &x[(size_t)(blk * 16 + xrow) * TLEN];
        f32x4 xr0[8];
        #pragma unroll
        for (int j = 0; j < 8; ++j)
            xr0[j] = *(const f32x4*)&xp[64 * j + 4 * xsl];
        #pragma unroll
        for (int j = 0; j < 8; ++j)
            *(f32x4*)&xs[xrow * XSF + 64 * j + 4 * xsl] = xr0[j];
    }

    // ---- issue W_hh loads early (f32 regs); convert after step 0 ----
    float wtmp[2][4][8];
    #pragma unroll
    for (int u = 0; u < 2; ++u)
        #pragma unroll
        for (int kc = 0; kc < 4; ++kc) {
            const int row = 32 * w + 16 * u + n;
            const float* wp = &Whh[row * HDIM + 32 * kc + 8 * q];
            const float4 f0 = *(const float4*)&wp[0];
            const float4 f1 = *(const float4*)&wp[4];
            wtmp[u][kc][0] = f0.x; wtmp[u][kc][1] = f0.y;
            wtmp[u][kc][2] = f0.z; wtmp[u][kc][3] = f0.w;
            wtmp[u][kc][4] = f1.x; wtmp[u][kc][5] = f1.y;
            wtmp[u][kc][6] = f1.z; wtmp[u][kc][7] = f1.w;
        }

    // per-lane row constants: acc element (u,r) -> row 32w + 16u + 4q + r
    float wx[8], bb[8];
    #pragma unroll
    for (int u = 0; u < 2; ++u)
        #pragma unroll
        for (int r = 0; r < 4; ++r) {
            const int row = 32 * w + 16 * u + 4 * q + r;
            wx[4 * u + r] = Whx[row];
            bb[4 * u + r] = bh[row];
        }

    __syncthreads();               // xs visible

    float accWh[8], h_prev[8], hv[8];
    #pragma unroll
    for (int i = 0; i < 8; ++i) { accWh[i] = 0.0f; h_prev[i] = 0.0f; }

    auto writeLimbs = [&](int par) {
        #pragma unroll
        for (int u = 0; u < 2; ++u) {
            PK4 p1, p2;
            #pragma unroll
            for (int r = 0; r < 4; ++r) {
                const float v = hv[4 * u + r];
                const _Float16 hh = (_Float16)v;
                p1.h[r] = hh;
                p2.h[r] = (_Float16)((v - (float)hh) * 2048.0f);
            }
            const int kb = 32 * w + 16 * u + 4 * q;
            *(uint2*)&hbuf[par * PARSTRIDE +              n * HS + kb] = p1.u;
            *(uint2*)&hbuf[par * PARSTRIDE + LIMBSTRIDE + n * HS + kb] = p2.u;
        }
    };

    // ---- step 0: h = 0 -> pre = wx*x0 + bb; no flags, no B, no MFMA ----
    {
        const float xt0 = xs[n * XSF + 0];
        float pre[8];
        #pragma unroll
        for (int i = 0; i < 8; ++i) pre[i] = fmaf(wx[i], xt0, bb[i]);
        bool sat = true;
        #pragma unroll
        for (int i = 0; i < 8; ++i) sat = sat && (fabsf(pre[i]) > 10.0f);
        const bool wave_sat = (__ballot(sat) == ~0ull);
        if (wave_sat) {
            #pragma unroll
            for (int i = 0; i < 8; ++i) hv[i] = copysignf(1.0f, pre[i]);
        } else {
            #pragma unroll
            for (int i = 0; i < 8; ++i) hv[i] = tanh_fast(pre[i]);
        }
        bool eq = true;
        #pragma unroll
        for (int i = 0; i < 8; ++i) eq = eq && (hv[i] == 0.0f);
        const bool wave_changed = (__ballot(eq) != ~0ull);
        #pragma unroll
        for (int i = 0; i < 8; ++i) h_prev[i] = hv[i];
        writeLimbs(1);
        if (lane == 0)
            ((unsigned char*)&flagw[1])[w] =
                (unsigned char)((wave_changed ? 1u : 0u) | (wave_sat ? 2u : 0u));
    }

    // ---- W-limb conversion (VALU; overlaps step-0 LDS drain) ----
    f16x8 w1[2][4], w2[2][4];
    #pragma unroll
    for (int u = 0; u < 2; ++u)
        #pragma unroll
        for (int kc = 0; kc < 4; ++kc)
            #pragma unroll
            for (int j = 0; j < 8; ++j) {
                const float v = wtmp[u][kc][j];
                const _Float16 a = (_Float16)v;
                w1[u][kc][j] = a;
                w2[u][kc][j] = (_Float16)((v - (float)a) * 2048.0f);
            }

    __syncthreads();               // step-0 h + flags visible

    int p  = 1;                    // parity of hbuf holding current h
    int sp = 1;                    // flag-word parity
    bool maskvalid = false;
    unsigned vm[16];

    int t = 1;
    while (t < TLEN) {
        const unsigned fw = flagw[sp];                 // issued first
        // unconditional B-fragment prefetch from hbuf[p] (current h);
        // latency overlaps flag wait; values discarded on light steps
        const _Float16* hb = &hbuf[p * PARSTRIDE];
        f16x8 b1[4], b2[4];
        #pragma unroll
        for (int kc = 0; kc < 4; ++kc) {
            b1[kc] = *(const f16x8*)&hb[             n * HS + 32 * kc + 8 * q];
            b2[kc] = *(const f16x8*)&hb[LIMBSTRIDE + n * HS + 32 * kc + 8 * q];
        }

        const bool heavy  = (fw & 0x01010101u) != 0u;  // someone's h changed
        const bool allsat = (fw & 0x02020202u) == 0x02020202u;
        if (heavy) maskvalid = false;                  // block-uniform
        bool do_heavy = heavy;

        if (!heavy && allsat) {
            // ---- stable: h frozen at exact +-1, accWh current ----
            if (!maskvalid) {
                if (tid < 16) { Xs[tid] = 0x7f800000u; vmask[tid] = 0u; }
                float m8 = 3.0e38f;
                #pragma unroll
                for (int i = 0; i < 8; ++i) {
                    const float c  = accWh[i] + bb[i];
                    const float mi = (c * h_prev[i] - 10.5f) / fmaxf(fabsf(wx[i]), 1e-30f);
                    m8 = fminf(m8, mi);
                }
                m8 = fmaxf(m8, 0.0f);                  // nonneg: uint order ok
                __syncthreads();
                atomicMin(&Xs[n], __float_as_uint(m8));
                __syncthreads();
                const float Xc = __uint_as_float(Xs[xrow]);
                const float* xrp = &xs[xrow * XSF];
                #pragma unroll
                for (int j = 0; j < 8; ++j) {
                    unsigned nib = 0u;
                    #pragma unroll
                    for (int m = 0; m < 4; ++m)
                        if (fabsf(xrp[64 * j + 4 * xsl + m]) >= Xc) nib |= (1u << m);
                    if (nib) atomicOr(&vmask[2 * j + (xsl >> 3)], nib << (4 * (xsl & 7)));
                }
                __syncthreads();
                #pragma unroll
                for (int k = 0; k < 4; ++k) {
                    const uint4 v4 = *(const uint4*)&vmask[4 * k];
                    vm[4 * k] = v4.x; vm[4 * k + 1] = v4.y;
                    vm[4 * k + 2] = v4.z; vm[4 * k + 3] = v4.w;
                }
                maskvalid = true;
            }
            // next violation >= t (register ffs; block-uniform)
            int nt = TLEN;
            #pragma unroll
            for (int wd = 15; wd >= 0; --wd) {
                const int base = 32 * wd;
                unsigned mm = vm[wd];
                mm = (base + 31 < t) ? 0u
                   : ((base < t) ? (mm & ~((1u << (t - base)) - 1u)) : mm);
                if (mm) nt = base + __ffs(mm) - 1;
            }
            if (nt >= TLEN) break;        // identity to the end
            t = nt;                       // steps [t, nt) are identity
            do_heavy = false;             // accWh current; light step at nt
        }

        // ---- execute one step at time t ----
        const float xt = xs[n * XSF + t];

        if (do_heavy) {
            #pragma unroll
            for (int u = 0; u < 2; ++u) {
                f32x4 a0  = {0.0f, 0.0f, 0.0f, 0.0f};
                f32x4 a1a = {0.0f, 0.0f, 0.0f, 0.0f};
                f32x4 a1b = {0.0f, 0.0f, 0.0f, 0.0f};
                #pragma unroll
                for (int kc = 0; kc < 4; ++kc) {
                    a0  = __builtin_amdgcn_mfma_f32_16x16x32_f16(w1[u][kc], b1[kc], a0,  0, 0, 0);
                    a1a = __builtin_amdgcn_mfma_f32_16x16x32_f16(w1[u][kc], b2[kc], a1a, 0, 0, 0);
                    a1b = __builtin_amdgcn_mfma_f32_16x16x32_f16(w2[u][kc], b1[kc], a1b, 0, 0, 0);
                }
                #pragma unroll
                for (int r = 0; r < 4; ++r)
                    accWh[4 * u + r] = fmaf(a1a[r] + a1b[r], 0x1p-11f, a0[r]);
            }
        }

        float pre[8];
        #pragma unroll
        for (int i = 0; i < 8; ++i)
            pre[i] = accWh[i] + fmaf(wx[i], xt, bb[i]);

        bool sat = true;
        #pragma unroll
        for (int i = 0; i < 8; ++i) sat = sat && (fabsf(pre[i]) > 10.0f);
        const bool wave_sat = (__ballot(sat) == ~0ull);
        if (wave_sat) {
            #pragma unroll
            for (int i = 0; i < 8; ++i) hv[i] = copysignf(1.0f, pre[i]);
        } else {
            #pragma unroll
            for (int i = 0; i < 8; ++i) hv[i] = tanh_fast(pre[i]);
        }

        bool eq = true;
        #pragma unroll
        for (int i = 0; i < 8; ++i) eq = eq && (hv[i] == h_prev[i]);
        const bool wave_changed = (__ballot(eq) != ~0ull);
        #pragma unroll
        for (int i = 0; i < 8; ++i) h_prev[i] = hv[i];

        if (do_heavy) {
            writeLimbs(p ^ 1);
            p ^= 1;
        } else if (wave_changed) {
            writeLimbs(p);   // p is the only parity ever read; same-step
                             // prefetch reads of p are discarded (light step)
        }
        if (lane == 0)
            ((unsigned char*)&flagw[sp ^ 1])[w] =
                (unsigned char)((wave_changed ? 1u : 0u) | (wave_sat ? 2u : 0u));
        __syncthreads();
        sp ^= 1;
        ++t;
    }

    // ---- projection: out[b][co] = sum_i Wph[co][i]*h_T[i][b] + bp[co] ----
    if (tid < 16 * NCLS) {
        const int c  = tid / NCLS;
        const int co = tid - c * NCLS;
        const int base = p * PARSTRIDE + c * HS;
        float s = bp[co];
        #pragma unroll
        for (int kc = 0; kc < 16; ++kc) {
            const f16x8 v1 = *(const f16x8*)&hbuf[base + 8 * kc];
            const f16x8 v2 = *(const f16x8*)&hbuf[base + LIMBSTRIDE + 8 * kc];
            #pragma unroll
            for (int j = 0; j < 8; ++j)
                s = fmaf(Wph[co * HDIM + 8 * kc + j],
                         (float)v1[j] + (float)v2[j] * (1.0f / 2048.0f), s);
        }
        out[((size_t)blk * 16 + c) * NCLS + co] = s;
    }
}

extern "C" void kernel_launch(void* const* d_in, const int* in_sizes, int n_in,
                              void* d_out, int out_size, void* d_ws, size_t ws_size,
                              hipStream_t stream) {
    const float* x   = (const float*)d_in[0];  // [4096,512]
    const float* Whx = (const float*)d_in[1];  // [128,1]
    const float* Whh = (const float*)d_in[2];  // [128,128]
    const float* Wph = (const float*)d_in[3];  // [10,128]
    const float* bh  = (const float*)d_in[4];  // [128,1]
    const float* bp  = (const float*)d_in[5];  // [10,1]
    float* out = (float*)d_out;                // [4096,10]

    rnn_kernel<<<dim3(256), dim3(256), 0, stream>>>(x, Whx, Whh, Wph, bh, bp, out);
}